// Round 12
// baseline (294.953 us; speedup 1.0000x reference)
//
#include <hip/hip_runtime.h>
#include <hip/hip_bf16.h>

// Fused attention block: qkv = x@Wqkv+b; attn; out = attn_out@Wfc+b
// B=2, N=4096, DIM=1024, H=16, D=64. bf16 MFMA, fp32 accum.

#define SEQ   4096
#define NHEAD 16
#define HDIM  64
#define FDIM  1024
#define BATCH 2
#define MTOT  (BATCH * SEQ)
// 0.125 (1/sqrt(64)) * log2(e): folded into q so softmax runs in base-2 domain.
#define QSCALE 0.1803368801111204f

typedef __attribute__((ext_vector_type(8)))  __bf16 bf16x8;
typedef __attribute__((ext_vector_type(4)))  __bf16 bf16x4;
typedef __attribute__((ext_vector_type(2)))  __bf16 bf16x2;
typedef __attribute__((ext_vector_type(4)))  float  f32x4;
typedef __attribute__((ext_vector_type(16))) float  f32x16;
typedef __attribute__((ext_vector_type(2)))  unsigned uint2v;
typedef __attribute__((ext_vector_type(4)))  unsigned uint4v;

__device__ __forceinline__ f32x4 mfma16(bf16x8 a, bf16x8 b, f32x4 c) {
    return __builtin_amdgcn_mfma_f32_16x16x32_bf16(a, b, c, 0, 0, 0);
}
__device__ __forceinline__ f32x16 mfma32(bf16x8 a, bf16x8 b, f32x16 c) {
    return __builtin_amdgcn_mfma_f32_32x32x16_bf16(a, b, c, 0, 0, 0);
}
__device__ __forceinline__ unsigned packbf2(float lo, float hi) {
    bf16x2 t; t[0] = (__bf16)lo; t[1] = (__bf16)hi;
    return __builtin_bit_cast(unsigned, t);
}
__device__ __forceinline__ bf16x8 fragu(unsigned a, unsigned b, unsigned c, unsigned d) {
    uint4v u = {a, b, c, d};
    return __builtin_bit_cast(bf16x8, u);
}
// raw v_exp_f32: 1 instruction (no denormal-safe expansion)
__device__ __forceinline__ float fexp2(float x) {
    float r; asm("v_exp_f32 %0, %1" : "=v"(r) : "v"(x)); return r;
}
// async global->LDS, 16B/lane; lds must be wave-uniform base (HW adds lane*16)
__device__ __forceinline__ void gload16(const void* g, void* l) {
    __builtin_amdgcn_global_load_lds(
        (const __attribute__((address_space(1))) unsigned*)g,
        (__attribute__((address_space(3))) unsigned*)l, 16, 0, 0);
}
__device__ __forceinline__ float fmax3(float a, float b, float c) {
    return fmaxf(fmaxf(a, b), c);   // clang fuses to v_max3_f32
}

// ---------------- cast x: fp32 -> bf16 ----------------
__global__ __launch_bounds__(256) void cast_x_kernel(const float* __restrict__ in,
                                                     __bf16* __restrict__ out, int n4) {
    int i = blockIdx.x * 256 + threadIdx.x;
    if (i < n4) {
        f32x4 v = reinterpret_cast<const f32x4*>(in)[i];
        bf16x4 o;
        #pragma unroll
        for (int j = 0; j < 4; ++j) o[j] = (__bf16)v[j];
        reinterpret_cast<bf16x4*>(out)[i] = o;
    }
}

// ---------------- transpose + cast W: (K x N) fp32 -> (N x K) bf16 ----------------
__global__ __launch_bounds__(256) void transpose_cast_kernel(const float* __restrict__ in,
                                                             __bf16* __restrict__ out,
                                                             int K, int N) {
    int nbk = K >> 6;
    int bn = blockIdx.x / nbk, bk = blockIdx.x % nbk;
    int n0 = bn * 64, k0 = bk * 64;
    __shared__ __bf16 tile[64][72];
    int t = threadIdx.x;
    #pragma unroll
    for (int p = 0; p < 4; ++p) {
        int c = t + p * 256;
        int kr = c >> 4, nc = (c & 15) * 4;
        f32x4 v = *reinterpret_cast<const f32x4*>(&in[(size_t)(k0 + kr) * N + n0 + nc]);
        #pragma unroll
        for (int j = 0; j < 4; ++j) tile[kr][nc + j] = (__bf16)v[j];
    }
    __syncthreads();
    #pragma unroll
    for (int p = 0; p < 2; ++p) {
        int c = t + p * 256;
        int nr = c >> 3, kc = (c & 7) * 8;
        bf16x8 o;
        #pragma unroll
        for (int j = 0; j < 8; ++j) o[j] = tile[kc + j][nr];
        *reinterpret_cast<bf16x8*>(&out[(size_t)(n0 + nr) * K + k0 + kc]) = o;
    }
}

// ---------------- GEMM: C = A(MxK) * Bt(NxK)^T + bias ----------------
// 2-phase double-buffered staging: issue next-tile global_load_lds before
// computing the current tile; counted s_waitcnt vmcnt(4) keeps the next tile's
// loads in flight across both barriers.
// MODE 0: scatter bf16 into q/k/v; q pre-scaled by QSCALE; v written transposed (B,H,D,N).
// MODE 1: fp32 output row-major
template <int MODE>
__global__ __launch_bounds__(256) void gemm_bt_kernel(const __bf16* __restrict__ A,
                                                      const __bf16* __restrict__ Bt,
                                                      const float* __restrict__ bias,
                                                      void* __restrict__ out,
                                                      int M, int N, int K, int nbn) {
    // XCD-aware swizzle (gridDim.x % 8 == 0 for all our launches)
    const int cpx = gridDim.x >> 3;
    const int wid = (blockIdx.x & 7) * cpx + (blockIdx.x >> 3);
    int bm = wid / nbn, bn = wid % nbn;
    int m0 = bm * 128, n0 = bn * 128;
    __shared__ __bf16 As[2][128 * 32];
    __shared__ __bf16 Bs[2][128 * 32];
    int t = threadIdx.x, lane = t & 63, w = t >> 6;
    int wr = w >> 1, wc = w & 1;
    int l15 = lane & 15, lk = (lane >> 4) * 8;

    f32x4 acc[4][4] = {};

    // staging geometry: chunk c = p*256 + t; row = c>>2; 8-elem chunk (c&3)
    const int r_c0 = t >> 2, kc_c0 = (t & 3) * 8;          // p=0
    const int r_c1 = (256 + t) >> 2, kc_c1 = (t & 3) * 8;  // p=1 (t&3 unchanged)
    const int lds0 = w * 1024;          // wave-uniform, p=0
    const int lds1 = 4096 + w * 1024;   // p=1

    #define GSTAGE(kt, buf)                                                       \
        do {                                                                      \
            char* ab = (char*)As[buf]; char* bb = (char*)Bs[buf];                 \
            gload16(&A[(size_t)(m0 + r_c0) * K + (kt) + kc_c0], ab + lds0);       \
            gload16(&A[(size_t)(m0 + r_c1) * K + (kt) + kc_c1], ab + lds1);       \
            gload16(&Bt[(size_t)(n0 + r_c0) * K + (kt) + kc_c0], bb + lds0);      \
            gload16(&Bt[(size_t)(n0 + r_c1) * K + (kt) + kc_c1], bb + lds1);      \
        } while (0)

    const int nt = K >> 5;
    GSTAGE(0, 0);

    for (int ti = 0; ti < nt; ++ti) {
        const int cur = ti & 1;
        if (ti + 1 < nt) {
            GSTAGE((ti + 1) << 5, cur ^ 1);
            // counted wait: 4 outstanding = tile ti+1's loads; tile ti's landed
            asm volatile("s_waitcnt vmcnt(4)" ::: "memory");
        } else {
            asm volatile("s_waitcnt vmcnt(0)" ::: "memory");
        }
        __builtin_amdgcn_sched_barrier(0);
        __builtin_amdgcn_s_barrier();       // all waves: tile ti staged
        __builtin_amdgcn_sched_barrier(0);

        bf16x8 af[4], bfv[4];
        #pragma unroll
        for (int fm = 0; fm < 4; ++fm)
            af[fm] = *reinterpret_cast<const bf16x8*>(&As[cur][(wr * 64 + fm * 16 + l15) * 32 + lk]);
        #pragma unroll
        for (int fn = 0; fn < 4; ++fn)
            bfv[fn] = *reinterpret_cast<const bf16x8*>(&Bs[cur][(wc * 64 + fn * 16 + l15) * 32 + lk]);
        #pragma unroll
        for (int fm = 0; fm < 4; ++fm)
            #pragma unroll
            for (int fn = 0; fn < 4; ++fn)
                acc[fm][fn] = mfma16(af[fm], bfv[fn], acc[fm][fn]);

        __builtin_amdgcn_sched_barrier(0);
        __builtin_amdgcn_s_barrier();       // all waves done with buf cur before overwrite
        __builtin_amdgcn_sched_barrier(0);
    }
    #undef GSTAGE

    #pragma unroll
    for (int fn = 0; fn < 4; ++fn) {
        int col = n0 + wc * 64 + fn * 16 + l15;
        float bi = bias[col];
        #pragma unroll
        for (int fm = 0; fm < 4; ++fm) {
            f32x4 c = acc[fm][fn];
            #pragma unroll
            for (int r = 0; r < 4; ++r) {
                int row = m0 + wr * 64 + fm * 16 + (lane >> 4) * 4 + r;
                float val = c[r] + bi;
                if (MODE == 0) {
                    int sel = col >> 10, h = (col >> 6) & 15, d = col & 63;
                    int b = row >> 12, nr = row & 4095;
                    if (sel == 0) val *= QSCALE;   // fold attn scale + log2e into q
                    __bf16* qkv = (__bf16*)out;
                    size_t addr;
                    if (sel == 2)   // v stored transposed: (B,H,D,N)
                        addr = 2ull * (BATCH * NHEAD * SEQ * HDIM) +
                               ((size_t)(b * NHEAD + h) * HDIM + d) * SEQ + nr;
                    else
                        addr = (size_t)sel * (BATCH * NHEAD * SEQ * HDIM) +
                               ((size_t)(b * NHEAD + h) * SEQ + nr) * HDIM + d;
                    qkv[addr] = (__bf16)val;
                } else {
                    ((float*)out)[(size_t)row * N + col] = val;
                }
            }
        }
    }
}

// ---------------- flash attention ----------------
// grid: (B*H) * (SEQ/256) = 512 blocks, XCD-swizzled; 256 threads = 4 waves;
// each wave owns 64 q rows (2 sub-blocks of 32). DEPTH-4 LDS ring, single
// barrier per KV tile, STAGE issued AFTER the barrier:
//   body_i = { vmcnt(4) [tile i landed]; barrier; STAGE(i+2 -> slot (i+2)&3);
//              QK(i) || deferred PV1(i-1); SM0(i); PV0(i) || SM1(i) -> pa1 }
// Cross-tile pipeline (T15-lite): qb1's PV is deferred one tile — its 12 MFMAs
// (register pa1 + V[(i-1)&3]) are independent of QK(i) and fill QK's ds_read/
// MFMA latency; the old serial PV1 tail disappears. Rescale ordering stays
// correct: PV1(i-1) precedes SM0/SM1(i)'s alpha-rescale of oacc[1]/lacc[1].
// Ring safety: readers in body i touch slots i&3, (i-1)&3; the furthest-ahead
// writer (skew<1 via the single barrier) touches (i+2)&3 — distinct mod 4.
// Swapped QK^T (lane owns q col); -m folded via rank-1 ones x (-m) MFMA;
// in-register P via pack+permlane32_swap; denominator via ones-MFMA.
__global__ __launch_bounds__(256, 2) void attn_kernel(const __bf16* __restrict__ q,
                                                      const __bf16* __restrict__ k,
                                                      const __bf16* __restrict__ vt,
                                                      __bf16* __restrict__ ao) {
    // XCD swizzle: 512 blocks -> 64 consecutive work items per XCD
    const int wid = ((blockIdx.x & 7) << 6) | (blockIdx.x >> 3);
    const int bh = wid >> 4;
    const int q0 = (wid & 15) * 256;
    const int b = bh >> 4, h = bh & 15;
    const __bf16* __restrict__ qp = q + (size_t)bh * SEQ * HDIM;
    const __bf16* __restrict__ kp = k + (size_t)bh * SEQ * HDIM;
    const __bf16* __restrict__ vtp = vt + (size_t)bh * SEQ * HDIM;

    __shared__ __bf16 Ks[4][64 * 64];   // [slot][key][d], 8KB each (depth-4 ring)
    __shared__ __bf16 Vs[4][64 * 64];   // [slot][d][key]

    const int t = threadIdx.x, lane = t & 63, w = t >> 6;   // w in 0..3
    const int l31 = lane & 31, hi = lane >> 5;

    // Q fragments (B-operand): lane holds Q[q0+w*64+qb*32+l31][c*16+hi*8 .. +8]
    bf16x8 qf[2][4];
    #pragma unroll
    for (int qb = 0; qb < 2; ++qb)
        #pragma unroll
        for (int c = 0; c < 4; ++c)
            qf[qb][c] = *reinterpret_cast<const bf16x8*>(
                &qp[(size_t)(q0 + w * 64 + qb * 32 + l31) * HDIM + c * 16 + hi * 8]);

    f32x16 oacc[2][2], lacc[2];
    #pragma unroll
    for (int qb = 0; qb < 2; ++qb) {
        #pragma unroll
        for (int r = 0; r < 16; ++r) {
            oacc[qb][0][r] = 0.f; oacc[qb][1][r] = 0.f; lacc[qb][r] = 0.f;
        }
    }
    float mrun[2] = {0.f, 0.f};

    // hoisted constants: zero C, ones B-frag (rowsum), ones A-frag (k=0 slot),
    // negm B-frag (k=0 slot carries -mrun; zero until first rescale)
    f32x16 zeroC;
    #pragma unroll
    for (int r = 0; r < 16; ++r) zeroC[r] = 0.f;
    const uint4v onesu = {0x3F803F80u, 0x3F803F80u, 0x3F803F80u, 0x3F803F80u};
    const bf16x8 onesf = __builtin_bit_cast(bf16x8, onesu);
    const bf16x8 onesA = fragu(hi ? 0u : 0x3F80u, 0u, 0u, 0u);
    bf16x8 negmf[2] = {fragu(0u,0u,0u,0u), fragu(0u,0u,0u,0u)};

    // staging: wave w covers rows [w*16, w*16+16) of each tile, 2 gloads each
    const int r8 = lane >> 3;
    const int swz8 = ((lane & 7) ^ r8) * 8;            // pre-swizzled source chunk
    size_t offK[2], offV[2];
    #pragma unroll
    for (int i = 0; i < 2; ++i) {
        int row = w * 16 + i * 8 + r8;
        offK[i] = (size_t)row * HDIM + swz8;
        offV[i] = (size_t)row * SEQ + swz8;
    }
    const int ldsW = w * 2048;                         // wave-uniform base (bytes)
    const int kread = (l31 & 7) << 4;                  // read-side row-XOR (bytes)

    #define STAGE(ti, buf)                                                        \
        do {                                                                      \
            const __bf16* kn = kp + (size_t)(ti) * 64 * HDIM;                     \
            const __bf16* vn = vtp + (size_t)(ti) * 64;                           \
            char* kbuf = (char*)Ks[buf]; char* vbuf = (char*)Vs[buf];             \
            _Pragma("unroll")                                                     \
            for (int i = 0; i < 2; ++i) {                                         \
                gload16(kn + offK[i], kbuf + ldsW + i * 1024);                    \
                gload16(vn + offV[i], vbuf + ldsW + i * 1024);                    \
            }                                                                     \
        } while (0)

    // softmax for one q-sub-block: max tree, deferred rescale (incl lacc),
    // exps, bf16 pack + permlane32_swap -> PV A-frags
    #define SOFTMAX(QB, S0, S1, PA)                                              \
        do {                                                                     \
            float m0 = fmax3(S0[0],  S0[1],  S0[2]);                             \
            float m1 = fmax3(S0[3],  S0[4],  S0[5]);                             \
            float m2 = fmax3(S0[6],  S0[7],  S0[8]);                             \
            float m3 = fmax3(S0[9],  S0[10], S0[11]);                            \
            float m4 = fmax3(S0[12], S0[13], S0[14]);                            \
            float m5 = fmax3(S0[15], S1[0],  S1[1]);                             \
            float m6 = fmax3(S1[2],  S1[3],  S1[4]);                             \
            float m7 = fmax3(S1[5],  S1[6],  S1[7]);                             \
            float m8 = fmax3(S1[8],  S1[9],  S1[10]);                            \
            float m9 = fmax3(S1[11], S1[12], S1[13]);                            \
            float ma = fmaxf(S1[14], S1[15]);                                    \
            float mx = fmax3(fmax3(m0, m1, m2), fmax3(m3, m4, m5),               \
                             fmax3(fmax3(m6, m7, m8), m9, ma));                  \
            mx = fmaxf(mx, __shfl_xor(mx, 32));                                  \
            if (!__all(mx <= 8.0f)) {                                            \
                float delta = fmaxf(mx, 0.f);                                    \
                float alpha = fexp2(-delta);                                     \
                mrun[QB] += delta;                                               \
                negmf[QB] = fragu(hi ? 0u : packbf2(-mrun[QB], 0.f), 0u,0u,0u);  \
                S0 -= delta; S1 -= delta;                                        \
                _Pragma("unroll")                                                \
                for (int r = 0; r < 16; ++r) {                                   \
                    int row = (r & 3) + 8 * (r >> 2) + 4 * hi;                   \
                    float ar = __shfl(alpha, row);                               \
                    oacc[QB][0][r] *= ar; oacc[QB][1][r] *= ar;                  \
                    lacc[QB][r] *= ar;                                           \
                }                                                                \
            }                                                                    \
            unsigned pk[16];                                                     \
            _Pragma("unroll")                                                    \
            for (int i = 0; i < 8; ++i)                                          \
                pk[i] = packbf2(fexp2(S0[2*i]), fexp2(S0[2*i+1]));               \
            _Pragma("unroll")                                                    \
            for (int i = 0; i < 8; ++i)                                          \
                pk[8+i] = packbf2(fexp2(S1[2*i]), fexp2(S1[2*i+1]));             \
            _Pragma("unroll")                                                    \
            for (int kb = 0; kb < 2; ++kb) {                                     \
                uint2v sA = __builtin_amdgcn_permlane32_swap(pk[kb*8+0], pk[kb*8+2], false, false); \
                uint2v sB = __builtin_amdgcn_permlane32_swap(pk[kb*8+1], pk[kb*8+3], false, false); \
                uint2v sC = __builtin_amdgcn_permlane32_swap(pk[kb*8+4], pk[kb*8+6], false, false); \
                uint2v sD = __builtin_amdgcn_permlane32_swap(pk[kb*8+5], pk[kb*8+7], false, false); \
                PA[kb*2+0] = fragu(sA[0], sB[0], sA[1], sB[1]);                  \
                PA[kb*2+1] = fragu(sC[0], sD[0], sC[1], sD[1]);                  \
            }                                                                    \
        } while (0)

    // QK for both sub-blocks from slot base KB (rank-1 -m init)
    #define QKALL(KB, SA0, SA1, SB0, SB1)                                        \
        do {                                                                     \
            SA0 = mfma32(onesA, negmf[0], zeroC);                                \
            SA1 = mfma32(onesA, negmf[0], zeroC);                                \
            SB0 = mfma32(onesA, negmf[1], zeroC);                                \
            SB1 = mfma32(onesA, negmf[1], zeroC);                                \
            _Pragma("unroll")                                                    \
            for (int c = 0; c < 4; ++c) {                                        \
                const int co = (c * 32 + hi * 16) ^ kread;                       \
                bf16x8 k0 = *reinterpret_cast<const bf16x8*>(KB + l31 * 128 + co);      \
                bf16x8 k1 = *reinterpret_cast<const bf16x8*>(KB + (32 + l31) * 128 + co);\
                SA0 = mfma32(k0, qf[0][c], SA0);                                 \
                SA1 = mfma32(k1, qf[0][c], SA1);                                 \
                SB0 = mfma32(k0, qf[1][c], SB0);                                 \
                SB1 = mfma32(k1, qf[1][c], SB1);                                 \
            }                                                                    \
        } while (0)

    // PV for sub-block QB from frags PA and V-slot base VB
    #define PVADD(QB, PA, VB)                                                    \
        do {                                                                     \
            _Pragma("unroll")                                                    \
            for (int kc = 0; kc < 4; ++kc) {                                     \
                const int co = (kc * 32 + hi * 16) ^ kread;                      \
                _Pragma("unroll")                                                \
                for (int db = 0; db < 2; ++db) {                                 \
                    bf16x8 vf = *reinterpret_cast<const bf16x8*>(                \
                        VB + (db * 32 + l31) * 128 + co);                        \
                    oacc[QB][db] = mfma32(PA[kc], vf, oacc[QB][db]);             \
                }                                                                \
                lacc[QB] = mfma32(PA[kc], onesf, lacc[QB]);                      \
            }                                                                    \
        } while (0)

    const int NT = SEQ / 64;
    bf16x8 pa1[4];   // deferred PV1 fragments (previous tile's qb1)

    // prologue: fill ring slots 0 and 1
    STAGE(0, 0);
    STAGE(1, 1);

    // ---- body 0 (peeled: no deferred PV1 yet) ----
    {
        asm volatile("s_waitcnt vmcnt(4)" ::: "memory");   // tile 0 landed
        __builtin_amdgcn_sched_barrier(0);
        __builtin_amdgcn_s_barrier();
        __builtin_amdgcn_sched_barrier(0);
        STAGE(2, 2);
        const char* kbase = (const char*)Ks[0];
        const char* vbase = (const char*)Vs[0];
        f32x16 sa0, sa1, sb0, sb1;
        QKALL(kbase, sa0, sa1, sb0, sb1);
        bf16x8 pa0[4];
        SOFTMAX(0, sa0, sa1, pa0);
        PVADD(0, pa0, vbase);
        SOFTMAX(1, sb0, sb1, pa1);   // pa1 saved; PV1 deferred to body 1
    }

    for (int ti = 1; ti < NT; ++ti) {
        if (ti + 1 < NT) {
            asm volatile("s_waitcnt vmcnt(4)" ::: "memory");  // tile ti landed
        } else {
            asm volatile("s_waitcnt vmcnt(0)" ::: "memory");
        }
        __builtin_amdgcn_sched_barrier(0);
        __builtin_amdgcn_s_barrier();   // all waves: tile ti staged everywhere
        __builtin_amdgcn_sched_barrier(0);
        if (ti + 2 < NT) STAGE(ti + 2, (ti + 2) & 3);

        const char* kbase = (const char*)Ks[ti & 3];
        const char* vbase = (const char*)Vs[ti & 3];
        const char* vprev = (const char*)Vs[(ti + 3) & 3];   // (ti-1)&3

        // ---- QK(ti) ; deferred PV1(ti-1) fills its latency (independent) ----
        f32x16 sa0, sa1, sb0, sb1;
        QKALL(kbase, sa0, sa1, sb0, sb1);
        PVADD(1, pa1, vprev);          // must precede SM0/SM1's alpha-rescale

        // ---- SM0(ti) -> pa0 ; PV0(ti) ; SM1(ti) -> pa1 (PV1 deferred) ----
        bf16x8 pa0[4];
        SOFTMAX(0, sa0, sa1, pa0);
        PVADD(0, pa0, vbase);
        SOFTMAX(1, sb0, sb1, pa1);
    }

    // ---- epilogue: deferred PV1 of the last tile ----
    {
        const char* vprev = (const char*)Vs[(NT - 1) & 3];
        PVADD(1, pa1, vprev);
    }
    #undef STAGE
    #undef SOFTMAX
    #undef QKALL
    #undef PVADD

    // ---- epilogue: normalize, store (B,N,H*D) bf16 ----
    #pragma unroll
    for (int qb = 0; qb < 2; ++qb) {
        #pragma unroll
        for (int r = 0; r < 16; ++r) {
            int row = (r & 3) + 8 * (r >> 2) + 4 * hi;
            float li = 1.0f / lacc[qb][r];   // rowsum(q=row), uniform over l31
            int qrow = q0 + w * 64 + qb * 32 + row;
            #pragma unroll
            for (int db = 0; db < 2; ++db) {
                int d = h * 64 + db * 32 + l31;
                ao[((size_t)(b * SEQ + qrow)) * FDIM + d] = (__bf16)(oacc[qb][db][r] * li);
            }
        }
    }
}

// ---------------- launcher ----------------
extern "C" void kernel_launch(void* const* d_in, const int* in_sizes, int n_in,
                              void* d_out, int out_size, void* d_ws, size_t ws_size,
                              hipStream_t stream) {
    const float* x    = (const float*)d_in[0];
    const float* Wqkv = (const float*)d_in[1];
    const float* bqkv = (const float*)d_in[2];
    const float* Wfc  = (const float*)d_in[3];
    const float* bfc  = (const float*)d_in[4];
    float* out = (float*)d_out;

    char* ws = (char*)d_ws;
    __bf16* xb    = (__bf16*)(ws + 0);
    __bf16* wqkvt = (__bf16*)(ws + 16777216);
    __bf16* wfct  = (__bf16*)(ws + 23068672);
    __bf16* qb    = (__bf16*)(ws + 25165824);
    __bf16* kb    = (__bf16*)(ws + 41943040);
    __bf16* vtb   = (__bf16*)(ws + 58720256);   // v written transposed by gemm
    __bf16* aob   = (__bf16*)(ws + 92274688);

    cast_x_kernel<<<8192, 256, 0, stream>>>(x, xb, (MTOT * FDIM) / 4);
    transpose_cast_kernel<<<(3 * FDIM / 64) * (FDIM / 64), 256, 0, stream>>>(Wqkv, wqkvt, FDIM, 3 * FDIM);
    transpose_cast_kernel<<<(FDIM / 64) * (FDIM / 64), 256, 0, stream>>>(Wfc, wfct, FDIM, FDIM);

    gemm_bt_kernel<0><<<(MTOT / 128) * (3 * FDIM / 128), 256, 0, stream>>>(
        xb, wqkvt, bqkv, (void*)qb, MTOT, 3 * FDIM, FDIM, 3 * FDIM / 128);

    attn_kernel<<<BATCH * NHEAD * (SEQ / 256), 256, 0, stream>>>(qb, kb, vtb, aob);

    gemm_bt_kernel<1><<<(MTOT / 128) * (FDIM / 128), 256, 0, stream>>>(
        aob, wfct, bfc, (void*)out, MTOT, FDIM, FDIM, FDIM / 128);
}

// Round 13
// 284.537 us; speedup vs baseline: 1.0366x; 1.0366x over previous
//
#include <hip/hip_runtime.h>
#include <hip/hip_bf16.h>

// Fused attention block: qkv = x@Wqkv+b; attn; out = attn_out@Wfc+b
// B=2, N=4096, DIM=1024, H=16, D=64. bf16 MFMA, fp32 accum.

#define SEQ   4096
#define NHEAD 16
#define HDIM  64
#define FDIM  1024
#define BATCH 2
#define MTOT  (BATCH * SEQ)
// 0.125 (1/sqrt(64)) * log2(e): folded into q so softmax runs in base-2 domain.
#define QSCALE 0.1803368801111204f

typedef __attribute__((ext_vector_type(8)))  __bf16 bf16x8;
typedef __attribute__((ext_vector_type(4)))  __bf16 bf16x4;
typedef __attribute__((ext_vector_type(2)))  __bf16 bf16x2;
typedef __attribute__((ext_vector_type(4)))  float  f32x4;
typedef __attribute__((ext_vector_type(16))) float  f32x16;
typedef __attribute__((ext_vector_type(2)))  unsigned uint2v;
typedef __attribute__((ext_vector_type(4)))  unsigned uint4v;

__device__ __forceinline__ f32x4 mfma16(bf16x8 a, bf16x8 b, f32x4 c) {
    return __builtin_amdgcn_mfma_f32_16x16x32_bf16(a, b, c, 0, 0, 0);
}
__device__ __forceinline__ f32x16 mfma32(bf16x8 a, bf16x8 b, f32x16 c) {
    return __builtin_amdgcn_mfma_f32_32x32x16_bf16(a, b, c, 0, 0, 0);
}
__device__ __forceinline__ unsigned packbf2(float lo, float hi) {
    bf16x2 t; t[0] = (__bf16)lo; t[1] = (__bf16)hi;
    return __builtin_bit_cast(unsigned, t);
}
__device__ __forceinline__ bf16x8 fragu(unsigned a, unsigned b, unsigned c, unsigned d) {
    uint4v u = {a, b, c, d};
    return __builtin_bit_cast(bf16x8, u);
}
// raw v_exp_f32: 1 instruction (no denormal-safe expansion)
__device__ __forceinline__ float fexp2(float x) {
    float r; asm("v_exp_f32 %0, %1" : "=v"(r) : "v"(x)); return r;
}
// async global->LDS, 16B/lane; lds must be wave-uniform base (HW adds lane*16)
__device__ __forceinline__ void gload16(const void* g, void* l) {
    __builtin_amdgcn_global_load_lds(
        (const __attribute__((address_space(1))) unsigned*)g,
        (__attribute__((address_space(3))) unsigned*)l, 16, 0, 0);
}
__device__ __forceinline__ float fmax3(float a, float b, float c) {
    return fmaxf(fmaxf(a, b), c);   // clang fuses to v_max3_f32
}

// ---------------- cast x: fp32 -> bf16 ----------------
__global__ __launch_bounds__(256) void cast_x_kernel(const float* __restrict__ in,
                                                     __bf16* __restrict__ out, int n4) {
    int i = blockIdx.x * 256 + threadIdx.x;
    if (i < n4) {
        f32x4 v = reinterpret_cast<const f32x4*>(in)[i];
        bf16x4 o;
        #pragma unroll
        for (int j = 0; j < 4; ++j) o[j] = (__bf16)v[j];
        reinterpret_cast<bf16x4*>(out)[i] = o;
    }
}

// ---------------- transpose + cast W: (K x N) fp32 -> (N x K) bf16 ----------------
__global__ __launch_bounds__(256) void transpose_cast_kernel(const float* __restrict__ in,
                                                             __bf16* __restrict__ out,
                                                             int K, int N) {
    int nbk = K >> 6;
    int bn = blockIdx.x / nbk, bk = blockIdx.x % nbk;
    int n0 = bn * 64, k0 = bk * 64;
    __shared__ __bf16 tile[64][72];
    int t = threadIdx.x;
    #pragma unroll
    for (int p = 0; p < 4; ++p) {
        int c = t + p * 256;
        int kr = c >> 4, nc = (c & 15) * 4;
        f32x4 v = *reinterpret_cast<const f32x4*>(&in[(size_t)(k0 + kr) * N + n0 + nc]);
        #pragma unroll
        for (int j = 0; j < 4; ++j) tile[kr][nc + j] = (__bf16)v[j];
    }
    __syncthreads();
    #pragma unroll
    for (int p = 0; p < 2; ++p) {
        int c = t + p * 256;
        int nr = c >> 3, kc = (c & 7) * 8;
        bf16x8 o;
        #pragma unroll
        for (int j = 0; j < 8; ++j) o[j] = tile[kc + j][nr];
        *reinterpret_cast<bf16x8*>(&out[(size_t)(n0 + nr) * K + k0 + kc]) = o;
    }
}

// ---------------- GEMM: C = A(MxK) * Bt(NxK)^T + bias ----------------
// 2-phase double-buffered staging: issue next-tile global_load_lds before
// computing the current tile; counted s_waitcnt vmcnt(4) keeps the next tile's
// loads in flight across both barriers.
// MODE 0: scatter bf16 into q/k/v; q pre-scaled by QSCALE; v written transposed (B,H,D,N).
// MODE 1: fp32 output row-major
template <int MODE>
__global__ __launch_bounds__(256) void gemm_bt_kernel(const __bf16* __restrict__ A,
                                                      const __bf16* __restrict__ Bt,
                                                      const float* __restrict__ bias,
                                                      void* __restrict__ out,
                                                      int M, int N, int K, int nbn) {
    // XCD-aware swizzle (gridDim.x % 8 == 0 for all our launches)
    const int cpx = gridDim.x >> 3;
    const int wid = (blockIdx.x & 7) * cpx + (blockIdx.x >> 3);
    int bm = wid / nbn, bn = wid % nbn;
    int m0 = bm * 128, n0 = bn * 128;
    __shared__ __bf16 As[2][128 * 32];
    __shared__ __bf16 Bs[2][128 * 32];
    int t = threadIdx.x, lane = t & 63, w = t >> 6;
    int wr = w >> 1, wc = w & 1;
    int l15 = lane & 15, lk = (lane >> 4) * 8;

    f32x4 acc[4][4] = {};

    // staging geometry: chunk c = p*256 + t; row = c>>2; 8-elem chunk (c&3)
    const int r_c0 = t >> 2, kc_c0 = (t & 3) * 8;          // p=0
    const int r_c1 = (256 + t) >> 2, kc_c1 = (t & 3) * 8;  // p=1 (t&3 unchanged)
    const int lds0 = w * 1024;          // wave-uniform, p=0
    const int lds1 = 4096 + w * 1024;   // p=1

    #define GSTAGE(kt, buf)                                                       \
        do {                                                                      \
            char* ab = (char*)As[buf]; char* bb = (char*)Bs[buf];                 \
            gload16(&A[(size_t)(m0 + r_c0) * K + (kt) + kc_c0], ab + lds0);       \
            gload16(&A[(size_t)(m0 + r_c1) * K + (kt) + kc_c1], ab + lds1);       \
            gload16(&Bt[(size_t)(n0 + r_c0) * K + (kt) + kc_c0], bb + lds0);      \
            gload16(&Bt[(size_t)(n0 + r_c1) * K + (kt) + kc_c1], bb + lds1);      \
        } while (0)

    const int nt = K >> 5;
    GSTAGE(0, 0);

    for (int ti = 0; ti < nt; ++ti) {
        const int cur = ti & 1;
        if (ti + 1 < nt) {
            GSTAGE((ti + 1) << 5, cur ^ 1);
            // counted wait: 4 outstanding = tile ti+1's loads; tile ti's landed
            asm volatile("s_waitcnt vmcnt(4)" ::: "memory");
        } else {
            asm volatile("s_waitcnt vmcnt(0)" ::: "memory");
        }
        __builtin_amdgcn_sched_barrier(0);
        __builtin_amdgcn_s_barrier();       // all waves: tile ti staged
        __builtin_amdgcn_sched_barrier(0);

        bf16x8 af[4], bfv[4];
        #pragma unroll
        for (int fm = 0; fm < 4; ++fm)
            af[fm] = *reinterpret_cast<const bf16x8*>(&As[cur][(wr * 64 + fm * 16 + l15) * 32 + lk]);
        #pragma unroll
        for (int fn = 0; fn < 4; ++fn)
            bfv[fn] = *reinterpret_cast<const bf16x8*>(&Bs[cur][(wc * 64 + fn * 16 + l15) * 32 + lk]);
        #pragma unroll
        for (int fm = 0; fm < 4; ++fm)
            #pragma unroll
            for (int fn = 0; fn < 4; ++fn)
                acc[fm][fn] = mfma16(af[fm], bfv[fn], acc[fm][fn]);

        __builtin_amdgcn_sched_barrier(0);
        __builtin_amdgcn_s_barrier();       // all waves done with buf cur before overwrite
        __builtin_amdgcn_sched_barrier(0);
    }
    #undef GSTAGE

    #pragma unroll
    for (int fn = 0; fn < 4; ++fn) {
        int col = n0 + wc * 64 + fn * 16 + l15;
        float bi = bias[col];
        #pragma unroll
        for (int fm = 0; fm < 4; ++fm) {
            f32x4 c = acc[fm][fn];
            #pragma unroll
            for (int r = 0; r < 4; ++r) {
                int row = m0 + wr * 64 + fm * 16 + (lane >> 4) * 4 + r;
                float val = c[r] + bi;
                if (MODE == 0) {
                    int sel = col >> 10, h = (col >> 6) & 15, d = col & 63;
                    int b = row >> 12, nr = row & 4095;
                    if (sel == 0) val *= QSCALE;   // fold attn scale + log2e into q
                    __bf16* qkv = (__bf16*)out;
                    size_t addr;
                    if (sel == 2)   // v stored transposed: (B,H,D,N)
                        addr = 2ull * (BATCH * NHEAD * SEQ * HDIM) +
                               ((size_t)(b * NHEAD + h) * HDIM + d) * SEQ + nr;
                    else
                        addr = (size_t)sel * (BATCH * NHEAD * SEQ * HDIM) +
                               ((size_t)(b * NHEAD + h) * SEQ + nr) * HDIM + d;
                    qkv[addr] = (__bf16)val;
                } else {
                    ((float*)out)[(size_t)row * N + col] = val;
                }
            }
        }
    }
}

// ---------------- flash attention ----------------
// grid: (B*H) * (SEQ/256) = 512 blocks, XCD-swizzled; 256 threads = 4 waves;
// each wave owns 64 q rows (2 sub-blocks of 32). DEPTH-4 LDS rotation with a
// SINGLE barrier per KV tile: body_i = { STAGE(i+2 -> buf (i+2)&3);
// s_waitcnt vmcnt(8); s_barrier; compute(i from buf i&3) }.
//   RAW: vmcnt(8) before the barrier leaves only tiles i+1,i+2 in flight, so
//        at the barrier ALL waves' tile-i loads have landed.
//   WAR: single barrier -> wave skew < 1 iter; the furthest-ahead wave writes
//        buf (i+3)&3 while the slowest reads buf i&3 — distinct at depth 4.
// Loads issue 2 compute-rounds ahead (full L2-latency cover). Schedule per
// tile: QK-all (K frags read once, feed both sub-blocks) -> SM0 -> PV0 -> SM1
// -> PV1. Swapped QK^T (lane owns q col); -m folded via rank-1 ones x (-m)
// MFMA; in-register P via pack+permlane32_swap; denominator via ones-MFMA.
// K/V staged via global_load_lds (pre-swizzled source, linear dest, XOR reads).
__global__ __launch_bounds__(256, 2) void attn_kernel(const __bf16* __restrict__ q,
                                                      const __bf16* __restrict__ k,
                                                      const __bf16* __restrict__ vt,
                                                      __bf16* __restrict__ ao) {
    // XCD swizzle: 512 blocks -> 64 consecutive work items per XCD
    const int wid = ((blockIdx.x & 7) << 6) | (blockIdx.x >> 3);
    const int bh = wid >> 4;
    const int q0 = (wid & 15) * 256;
    const int b = bh >> 4, h = bh & 15;
    const __bf16* __restrict__ qp = q + (size_t)bh * SEQ * HDIM;
    const __bf16* __restrict__ kp = k + (size_t)bh * SEQ * HDIM;
    const __bf16* __restrict__ vtp = vt + (size_t)bh * SEQ * HDIM;

    __shared__ __bf16 Ks[4][64 * 64];   // [buf][key][d], 8KB each (depth-4 ring)
    __shared__ __bf16 Vs[4][64 * 64];   // [buf][d][key]

    const int t = threadIdx.x, lane = t & 63, w = t >> 6;   // w in 0..3
    const int l31 = lane & 31, hi = lane >> 5;

    // Q fragments (B-operand): lane holds Q[q0+w*64+qb*32+l31][c*16+hi*8 .. +8]
    bf16x8 qf[2][4];
    #pragma unroll
    for (int qb = 0; qb < 2; ++qb)
        #pragma unroll
        for (int c = 0; c < 4; ++c)
            qf[qb][c] = *reinterpret_cast<const bf16x8*>(
                &qp[(size_t)(q0 + w * 64 + qb * 32 + l31) * HDIM + c * 16 + hi * 8]);

    f32x16 oacc[2][2], lacc[2];
    #pragma unroll
    for (int qb = 0; qb < 2; ++qb) {
        #pragma unroll
        for (int r = 0; r < 16; ++r) {
            oacc[qb][0][r] = 0.f; oacc[qb][1][r] = 0.f; lacc[qb][r] = 0.f;
        }
    }
    float mrun[2] = {0.f, 0.f};

    // hoisted constants: zero C, ones B-frag (rowsum), ones A-frag (k=0 slot),
    // negm B-frag (k=0 slot carries -mrun; zero until first rescale)
    f32x16 zeroC;
    #pragma unroll
    for (int r = 0; r < 16; ++r) zeroC[r] = 0.f;
    const uint4v onesu = {0x3F803F80u, 0x3F803F80u, 0x3F803F80u, 0x3F803F80u};
    const bf16x8 onesf = __builtin_bit_cast(bf16x8, onesu);
    const bf16x8 onesA = fragu(hi ? 0u : 0x3F80u, 0u, 0u, 0u);
    bf16x8 negmf[2] = {fragu(0u,0u,0u,0u), fragu(0u,0u,0u,0u)};

    // staging: wave w covers rows [w*16, w*16+16) of each tile, 2 gloads each
    const int r8 = lane >> 3;
    const int swz8 = ((lane & 7) ^ r8) * 8;            // pre-swizzled source chunk
    size_t offK[2], offV[2];
    #pragma unroll
    for (int i = 0; i < 2; ++i) {
        int row = w * 16 + i * 8 + r8;
        offK[i] = (size_t)row * HDIM + swz8;
        offV[i] = (size_t)row * SEQ + swz8;
    }
    const int ldsW = w * 2048;                         // wave-uniform base (bytes)
    const int kread = (l31 & 7) << 4;                  // read-side row-XOR (bytes)

    #define STAGE(ti, buf)                                                        \
        do {                                                                      \
            const __bf16* kn = kp + (size_t)(ti) * 64 * HDIM;                     \
            const __bf16* vn = vtp + (size_t)(ti) * 64;                           \
            char* kbuf = (char*)Ks[buf]; char* vbuf = (char*)Vs[buf];             \
            _Pragma("unroll")                                                     \
            for (int i = 0; i < 2; ++i) {                                         \
                gload16(kn + offK[i], kbuf + ldsW + i * 1024);                    \
                gload16(vn + offV[i], vbuf + ldsW + i * 1024);                    \
            }                                                                     \
        } while (0)

    // softmax for one q-sub-block: max tree, deferred rescale (incl lacc),
    // exps, bf16 pack + permlane32_swap -> PV A-frags
    #define SOFTMAX(QB, S0, S1, PA)                                              \
        do {                                                                     \
            float m0 = fmax3(S0[0],  S0[1],  S0[2]);                             \
            float m1 = fmax3(S0[3],  S0[4],  S0[5]);                             \
            float m2 = fmax3(S0[6],  S0[7],  S0[8]);                             \
            float m3 = fmax3(S0[9],  S0[10], S0[11]);                            \
            float m4 = fmax3(S0[12], S0[13], S0[14]);                            \
            float m5 = fmax3(S0[15], S1[0],  S1[1]);                             \
            float m6 = fmax3(S1[2],  S1[3],  S1[4]);                             \
            float m7 = fmax3(S1[5],  S1[6],  S1[7]);                             \
            float m8 = fmax3(S1[8],  S1[9],  S1[10]);                            \
            float m9 = fmax3(S1[11], S1[12], S1[13]);                            \
            float ma = fmaxf(S1[14], S1[15]);                                    \
            float mx = fmax3(fmax3(m0, m1, m2), fmax3(m3, m4, m5),               \
                             fmax3(fmax3(m6, m7, m8), m9, ma));                  \
            mx = fmaxf(mx, __shfl_xor(mx, 32));                                  \
            if (!__all(mx <= 8.0f)) {                                            \
                float delta = fmaxf(mx, 0.f);                                    \
                float alpha = fexp2(-delta);                                     \
                mrun[QB] += delta;                                               \
                negmf[QB] = fragu(hi ? 0u : packbf2(-mrun[QB], 0.f), 0u,0u,0u);  \
                S0 -= delta; S1 -= delta;                                        \
                _Pragma("unroll")                                                \
                for (int r = 0; r < 16; ++r) {                                   \
                    int row = (r & 3) + 8 * (r >> 2) + 4 * hi;                   \
                    float ar = __shfl(alpha, row);                               \
                    oacc[QB][0][r] *= ar; oacc[QB][1][r] *= ar;                  \
                    lacc[QB][r] *= ar;                                           \
                }                                                                \
            }                                                                    \
            unsigned pk[16];                                                     \
            _Pragma("unroll")                                                    \
            for (int i = 0; i < 8; ++i)                                          \
                pk[i] = packbf2(fexp2(S0[2*i]), fexp2(S0[2*i+1]));               \
            _Pragma("unroll")                                                    \
            for (int i = 0; i < 8; ++i)                                          \
                pk[8+i] = packbf2(fexp2(S1[2*i]), fexp2(S1[2*i+1]));             \
            _Pragma("unroll")                                                    \
            for (int kb = 0; kb < 2; ++kb) {                                     \
                uint2v sA = __builtin_amdgcn_permlane32_swap(pk[kb*8+0], pk[kb*8+2], false, false); \
                uint2v sB = __builtin_amdgcn_permlane32_swap(pk[kb*8+1], pk[kb*8+3], false, false); \
                uint2v sC = __builtin_amdgcn_permlane32_swap(pk[kb*8+4], pk[kb*8+6], false, false); \
                uint2v sD = __builtin_amdgcn_permlane32_swap(pk[kb*8+5], pk[kb*8+7], false, false); \
                PA[kb*2+0] = fragu(sA[0], sB[0], sA[1], sB[1]);                  \
                PA[kb*2+1] = fragu(sC[0], sD[0], sC[1], sD[1]);                  \
            }                                                                    \
        } while (0)

    // prologue: fill ring slots 0 and 1
    STAGE(0, 0);
    STAGE(1, 1);

    const int NT = SEQ / 64;
    for (int ti = 0; ti < NT; ++ti) {
        const int cur = ti & 3;
        if (ti + 2 < NT) {
            STAGE(ti + 2, (ti + 2) & 3);
            // outstanding after stage: tiles ti+1 (4) + ti+2 (4) = 8 -> ti landed
            asm volatile("s_waitcnt vmcnt(8)" ::: "memory");
        } else if (ti + 1 < NT) {
            asm volatile("s_waitcnt vmcnt(4)" ::: "memory");   // only ti+1 in flight
        } else {
            asm volatile("s_waitcnt vmcnt(0)" ::: "memory");
        }
        __builtin_amdgcn_sched_barrier(0);
        __builtin_amdgcn_s_barrier();   // all waves: tile ti staged everywhere
        __builtin_amdgcn_sched_barrier(0);

        const char* kbase = (const char*)Ks[cur];
        const char* vbase = (const char*)Vs[cur];

        // ---- QK^T for BOTH q-sub-blocks; K frags read once (rank-1 -m init) ----
        f32x16 sa0 = mfma32(onesA, negmf[0], zeroC);
        f32x16 sa1 = mfma32(onesA, negmf[0], zeroC);
        f32x16 sb0 = mfma32(onesA, negmf[1], zeroC);
        f32x16 sb1 = mfma32(onesA, negmf[1], zeroC);
        #pragma unroll
        for (int c = 0; c < 4; ++c) {
            const int co = (c * 32 + hi * 16) ^ kread;
            bf16x8 k0 = *reinterpret_cast<const bf16x8*>(kbase + l31 * 128 + co);
            bf16x8 k1 = *reinterpret_cast<const bf16x8*>(kbase + (32 + l31) * 128 + co);
            sa0 = mfma32(k0, qf[0][c], sa0);
            sa1 = mfma32(k1, qf[0][c], sa1);
            sb0 = mfma32(k0, qf[1][c], sb0);
            sb1 = mfma32(k1, qf[1][c], sb1);
        }

        // ---- SM0 ----
        bf16x8 pa0[4];
        SOFTMAX(0, sa0, sa1, pa0);

        // ---- PV qb0 + lacc0 (independent of SM1 -> compiler overlaps) ----
        #pragma unroll
        for (int kc = 0; kc < 4; ++kc) {
            const int co = (kc * 32 + hi * 16) ^ kread;
            #pragma unroll
            for (int db = 0; db < 2; ++db) {
                bf16x8 vf = *reinterpret_cast<const bf16x8*>(
                    vbase + (db * 32 + l31) * 128 + co);
                oacc[0][db] = mfma32(pa0[kc], vf, oacc[0][db]);
            }
            lacc[0] = mfma32(pa0[kc], onesf, lacc[0]);
        }

        // ---- SM1 (overlaps PV qb0 MFMA latency) ----
        bf16x8 pa1[4];
        SOFTMAX(1, sb0, sb1, pa1);

        // ---- PV qb1 + lacc1 ----
        #pragma unroll
        for (int kc = 0; kc < 4; ++kc) {
            const int co = (kc * 32 + hi * 16) ^ kread;
            #pragma unroll
            for (int db = 0; db < 2; ++db) {
                bf16x8 vf = *reinterpret_cast<const bf16x8*>(
                    vbase + (db * 32 + l31) * 128 + co);
                oacc[1][db] = mfma32(pa1[kc], vf, oacc[1][db]);
            }
            lacc[1] = mfma32(pa1[kc], onesf, lacc[1]);
        }
        // no trailing barrier: depth-4 ring makes next STAGE target WAR-safe
    }
    #undef STAGE
    #undef SOFTMAX

    // ---- epilogue: normalize, store (B,N,H*D) bf16 ----
    #pragma unroll
    for (int qb = 0; qb < 2; ++qb) {
        #pragma unroll
        for (int r = 0; r < 16; ++r) {
            int row = (r & 3) + 8 * (r >> 2) + 4 * hi;
            float li = 1.0f / lacc[qb][r];   // rowsum(q=row), uniform over l31
            int qrow = q0 + w * 64 + qb * 32 + row;
            #pragma unroll
            for (int db = 0; db < 2; ++db) {
                int d = h * 64 + db * 32 + l31;
                ao[((size_t)(b * SEQ + qrow)) * FDIM + d] = (__bf16)(oacc[qb][db][r] * li);
            }
        }
    }
}

// ---------------- launcher ----------------
extern "C" void kernel_launch(void* const* d_in, const int* in_sizes, int n_in,
                              void* d_out, int out_size, void* d_ws, size_t ws_size,
                              hipStream_t stream) {
    const float* x    = (const float*)d_in[0];
    const float* Wqkv = (const float*)d_in[1];
    const float* bqkv = (const float*)d_in[2];
    const float* Wfc  = (const float*)d_in[3];
    const float* bfc  = (const float*)d_in[4];
    float* out = (float*)d_out;

    char* ws = (char*)d_ws;
    __bf16* xb    = (__bf16*)(ws + 0);
    __bf16* wqkvt = (__bf16*)(ws + 16777216);
    __bf16* wfct  = (__bf16*)(ws + 23068672);
    __bf16* qb    = (__bf16*)(ws + 25165824);
    __bf16* kb    = (__bf16*)(ws + 41943040);
    __bf16* vtb   = (__bf16*)(ws + 58720256);   // v written transposed by gemm
    __bf16* aob   = (__bf16*)(ws + 92274688);

    cast_x_kernel<<<8192, 256, 0, stream>>>(x, xb, (MTOT * FDIM) / 4);
    transpose_cast_kernel<<<(3 * FDIM / 64) * (FDIM / 64), 256, 0, stream>>>(Wqkv, wqkvt, FDIM, 3 * FDIM);
    transpose_cast_kernel<<<(FDIM / 64) * (FDIM / 64), 256, 0, stream>>>(Wfc, wfct, FDIM, FDIM);

    gemm_bt_kernel<0><<<(MTOT / 128) * (3 * FDIM / 128), 256, 0, stream>>>(
        xb, wqkvt, bqkv, (void*)qb, MTOT, 3 * FDIM, FDIM, 3 * FDIM / 128);

    attn_kernel<<<BATCH * NHEAD * (SEQ / 256), 256, 0, stream>>>(qb, kb, vtb, aob);

    gemm_bt_kernel<1><<<(MTOT / 128) * (FDIM / 128), 256, 0, stream>>>(
        aob, wfct, bfc, (void*)out, MTOT, FDIM, FDIM, FDIM / 128);
}